// Round 4
// baseline (2787.940 us; speedup 1.0000x reference)
//
#include <hip/hip_runtime.h>
#include <hip/hip_bf16.h>

#define B_ 8
#define S_ 128
#define H_ 512
#define E_ 512
#define NST 8
#define R_ 1024         // B_*S_ flat rows
#define N2 2048         // T/XO row width

typedef __hip_bfloat16 bf16;

__device__ __forceinline__ float sigm(float x){ return 1.0f/(1.0f + expf(-x)); }
__device__ __forceinline__ float load_in(const void* p, long long i, int isb){
    return isb ? __bfloat162float(((const bf16*)p)[i]) : ((const float*)p)[i];
}
// logical element j of an int tensor that may be stored int32 or int64 (little-endian)
__device__ __forceinline__ int idx_read(const int* p, int j, int is64){
    return is64 ? p[2*j] : p[j];
}

// ---- per-tensor float-storage probe: flags[b]=1 if bf16-stored, 0 if fp32-stored ----
// fp32 misread as u16 stream: mantissa-low halves have uniform exponent fields ->
// ~45%/probe have e>=140. True bf16 weights/emb (|v|<0.5) never do.
__global__ void probe_f(const void* t0, const void* t1, const void* t2, const void* t3,
                        const void* t4, const void* t5, const void* t6, const void* t7,
                        const void* t8, const void* t9, const void* t10, const void* t11,
                        const void* t12, const void* t13, const void* t14,
                        int* __restrict__ flags){
    const void* ts[15] = {t0,t1,t2,t3,t4,t5,t6,t7,t8,t9,t10,t11,t12,t13,t14};
    const unsigned short* u = (const unsigned short*)ts[blockIdx.x];
    int t = threadIdx.x;      // 512 threads
    int e = (u[t] >> 7) & 0xFF;
    unsigned long long b = __ballot(e >= 140);
    __shared__ int acc[8];
    if ((t & 63) == 0) acc[t >> 6] = (b != 0ull) ? 1 : 0;
    __syncthreads();
    if (t == 0){
        int any = 0;
        for (int w = 0; w < 8; ++w) any |= acc[w];
        flags[blockIdx.x] = any ? 0 : 1;
    }
}

// ---- int width probe: flags[16+b]=1 if int64-stored (all odd int32 words zero) ----
__global__ void probe_i(const int* __restrict__ ids, const int* __restrict__ tree,
                        int* __restrict__ flags){
    const int* p = (blockIdx.x == 0) ? ids : tree;
    int n = (blockIdx.x == 0) ? 1024 : 2048;
    int t = threadIdx.x;   // 1024
    int nz = 0;
    for (int j = t; j < n; j += 1024)
        if (j & 1) nz |= (p[j] != 0);
    unsigned long long b = __ballot(nz);
    __shared__ int acc[16];
    if ((t & 63) == 0) acc[t >> 6] = (b != 0ull) ? 1 : 0;
    __syncthreads();
    if (t == 0){
        int any = 0;
        for (int w = 0; w < 16; ++w) any |= acc[w];
        flags[16 + blockIdx.x] = any ? 0 : 1;
    }
}

// ---- serial per-step mask+rank (trivially correct; GLOBAL compaction order) ----
__global__ void rank_seq(const int* __restrict__ tree, int* __restrict__ msk,
                         int* __restrict__ rnk, const int* __restrict__ flags){
    int is64 = flags[17];
    int st = blockIdx.x;     // one thread per step
    int cnt = 0;
    for (int r = 0; r < R_; ++r){
        int b = r >> 7, s = r & 127;
        int idx_d = idx_read(tree, ((b*NST + st)*3 + 0)*S_ + s, is64);
        int m = (idx_d != 0) ? 1 : 0;
        msk[st*R_ + r] = m;
        rnk[st*R_ + r] = m ? cnt : 0;
        cnt += m;
    }
}

// ---- XO[m][n]: n<1536 -> x@W_ioux ; n>=1536 -> x@W_fx.  x gathered from emb. ----
__global__ __launch_bounds__(256)
void xo_kernel(const int* __restrict__ ids, const void* __restrict__ emb,
               const void* __restrict__ Wioux, const void* __restrict__ Wfx,
               float* __restrict__ XO, const int* __restrict__ flags){
    int f_emb = flags[0], f_wx = flags[1], f_wf = flags[6], i64 = flags[16];
    int m = blockIdx.x;
    int n = blockIdx.y*256 + threadIdx.x;
    __shared__ float xr[E_];
    long long base = (long long)idx_read(ids, m, i64)*E_;
    for (int k = threadIdx.x; k < E_; k += 256) xr[k] = load_in(emb, base + k, f_emb);
    __syncthreads();
    float a0 = 0.f, a1 = 0.f;
    if (n < 1536){
        for (int k = 0; k < E_; k += 2){
            a0 += xr[k]  *load_in(Wioux, (long long)k*1536 + n, f_wx);
            a1 += xr[k+1]*load_in(Wioux, (long long)(k+1)*1536 + n, f_wx);
        }
    } else {
        int c = n - 1536;
        for (int k = 0; k < E_; k += 2){
            a0 += xr[k]  *load_in(Wfx, (long long)k*512 + c, f_wf);
            a1 += xr[k+1]*load_in(Wfx, (long long)(k+1)*512 + c, f_wf);
        }
    }
    XO[(long long)m*N2 + n] = a0 + a1;
}

// ---- T[m][n] = h[m] @ col n of [Wr[:,:512] | Wl[:,:512] | Wfh0+Wfh1 | Wfh2+Wfh3] + bias ----
__global__ __launch_bounds__(256)
void t_kernel(const float* __restrict__ h,
              const void* __restrict__ Wr, const void* __restrict__ Wl,
              const void* __restrict__ W0, const void* __restrict__ W1,
              const void* __restrict__ W2, const void* __restrict__ W3,
              const void* __restrict__ br, const void* __restrict__ bl,
              const void* __restrict__ b0, const void* __restrict__ b1,
              const void* __restrict__ b2, const void* __restrict__ b3,
              float* __restrict__ T, const int* __restrict__ flags){
    int fWr=flags[2], fbr=flags[3], fWl=flags[4], fbl=flags[5];
    int fW0=flags[7], fb0=flags[8], fW1=flags[9], fb1=flags[10];
    int fW2=flags[11], fb2=flags[12], fW3=flags[13], fb3=flags[14];
    int m = blockIdx.x;
    int n = blockIdx.y*256 + threadIdx.x;
    __shared__ float hr[H_];
    for (int k = threadIdx.x; k < H_; k += 256) hr[k] = h[(long long)m*H_ + k];
    __syncthreads();
    float a0 = 0.f, a1 = 0.f, bia = 0.f;
    if (n < 512){
        for (int k = 0; k < H_; k += 2){
            a0 += hr[k]  *load_in(Wr, (long long)k*1536 + n, fWr);
            a1 += hr[k+1]*load_in(Wr, (long long)(k+1)*1536 + n, fWr);
        }
        bia = load_in(br, n, fbr);
    } else if (n < 1024){
        int c = n - 512;
        for (int k = 0; k < H_; k += 2){
            a0 += hr[k]  *load_in(Wl, (long long)k*1536 + c, fWl);
            a1 += hr[k+1]*load_in(Wl, (long long)(k+1)*1536 + c, fWl);
        }
        bia = load_in(bl, c, fbl);
    } else if (n < 1536){
        int c = n - 1024;
        for (int k = 0; k < H_; k += 2){
            a0 += hr[k]  *(load_in(W0, (long long)k*512 + c, fW0) + load_in(W1, (long long)k*512 + c, fW1));
            a1 += hr[k+1]*(load_in(W0, (long long)(k+1)*512 + c, fW0) + load_in(W1, (long long)(k+1)*512 + c, fW1));
        }
        bia = load_in(b0, c, fb0) + load_in(b1, c, fb1);
    } else {
        int c = n - 1536;
        for (int k = 0; k < H_; k += 2){
            a0 += hr[k]  *(load_in(W2, (long long)k*512 + c, fW2) + load_in(W3, (long long)k*512 + c, fW3));
            a1 += hr[k+1]*(load_in(W2, (long long)(k+1)*512 + c, fW2) + load_in(W3, (long long)(k+1)*512 + c, fW3));
        }
        bia = load_in(b2, c, fb2) + load_in(b3, c, fb3);
    }
    T[(long long)m*N2 + n] = a0 + a1 + bia;
}

// ---- f-gate + the three scatter-adds (atomics), literal ----
__global__ __launch_bounds__(256)
void scat_kernel(const int* __restrict__ tree, int st,
                 const float* __restrict__ T, const float* __restrict__ XO,
                 const float* __restrict__ c_cur,
                 float* __restrict__ scat, float* __restrict__ c_scat,
                 const int* __restrict__ flags){
    int is64 = flags[17];
    int r = blockIdx.x;
    int b = r >> 7, s = r & 127;
    int base = (b*NST + st)*3*S_;
    int rd = (b<<7) + idx_read(tree, base + s, is64);
    int rr = (b<<7) + idx_read(tree, base + S_ + s, is64);
    int rl = (b<<7) + idx_read(tree, base + 2*S_ + s, is64);
    for (int c = threadIdx.x; c < H_; c += 256){
        float f = sigm(XO[(long long)rd*N2 + 1536 + c]
                     + T [(long long)rr*N2 + 1024 + c]
                     + T [(long long)rl*N2 + 1536 + c]);
        atomicAdd(&c_scat[(long long)rd*H_ + c], f * c_cur[(long long)r*H_ + c]);
        atomicAdd(&scat  [(long long)rr*H_ + c], T[(long long)r*N2 + c]);
        atomicAdd(&scat  [(long long)rl*H_ + c], T[(long long)r*N2 + 512 + c]);
    }
}

// ---- gates + c_full/h_full for ALL rows ----
__global__ __launch_bounds__(256)
void full_kernel(const float* __restrict__ XO, const float* __restrict__ scat,
                 const float* __restrict__ c_scat,
                 float* __restrict__ hfull, float* __restrict__ cfull){
    int r = blockIdx.x;
    const float* xo = XO + (long long)r*N2;
    for (int c = threadIdx.x; c < H_; c += 256){
        float ig = sigm(xo[c] + scat[(long long)r*H_ + c]);
        float og = sigm(xo[512 + c]);
        float ug = tanhf(xo[1024 + c]);
        float cf = ig*ug + c_scat[(long long)r*H_ + c];
        cfull[(long long)r*H_ + c] = cf;
        hfull[(long long)r*H_ + c] = og * tanhf(cf);
    }
}

// ---- masked scatter as gather: row r takes full[rank(r)] if masked, else old ----
__global__ __launch_bounds__(256)
void ms_kernel(const float* __restrict__ hfull, const float* __restrict__ cfull,
               const float* __restrict__ h_old, const float* __restrict__ c_old,
               float* __restrict__ h_new, float* __restrict__ c_new,
               const int* __restrict__ msk, const int* __restrict__ rnk, int st){
    int r = blockIdx.x;
    int m = msk[st*R_ + r];
    int k = rnk[st*R_ + r];
    const float* hs = m ? (hfull + (long long)k*H_) : (h_old + (long long)r*H_);
    const float* cs = m ? (cfull + (long long)k*H_) : (c_old + (long long)r*H_);
    for (int c = threadIdx.x; c < H_; c += 256){
        h_new[(long long)r*H_ + c] = hs[c];
        c_new[(long long)r*H_ + c] = cs[c];
    }
}

extern "C" void kernel_launch(void* const* d_in, const int* in_sizes, int n_in,
                              void* d_out, int out_size, void* d_ws, size_t ws_size,
                              hipStream_t stream) {
    const int*  input_ids = (const int*)d_in[0];
    const int*  tree      = (const int*)d_in[1];

    char* p = (char*)d_ws;
    auto alloc = [&](size_t bytes) -> void* {
        void* q = (void*)p;
        p += (bytes + 255) & ~(size_t)255;
        return q;
    };
    float* XO     = (float*)alloc((size_t)R_*N2*4);   // 8 MB
    float* T      = (float*)alloc((size_t)R_*N2*4);   // 8 MB (hfull/cfull overlay)
    float* scat   = (float*)alloc((size_t)R_*H_*4);   // 2 MB (contiguous with c_scat)
    float* c_scat = (float*)alloc((size_t)R_*H_*4);   // 2 MB
    float* h0     = (float*)alloc((size_t)R_*H_*4);   // contiguous with c0
    float* c0     = (float*)alloc((size_t)R_*H_*4);
    float* h1     = (float*)alloc((size_t)R_*H_*4);
    float* c1     = (float*)alloc((size_t)R_*H_*4);
    int*   msk    = (int*)alloc((size_t)NST*R_*4);
    int*   rnk    = (int*)alloc((size_t)NST*R_*4);
    int*   flags  = (int*)alloc(256);
    // hfull/cfull overlay T: T is dead after scat_kernel each step, rewritten next step.
    float* hfull  = T;
    float* cfull  = T + (size_t)R_*H_;

    hipLaunchKernelGGL(probe_f, dim3(15), dim3(512), 0, stream,
                       d_in[2], d_in[3], d_in[4], d_in[5], d_in[6], d_in[7], d_in[8],
                       d_in[9], d_in[10], d_in[11], d_in[12], d_in[13], d_in[14],
                       d_in[15], d_in[16], flags);
    hipLaunchKernelGGL(probe_i, dim3(2), dim3(1024), 0, stream, input_ids, tree, flags);
    hipLaunchKernelGGL(rank_seq, dim3(NST), dim3(1), 0, stream, tree, msk, rnk, flags);
    hipMemsetAsync(h0, 0, (size_t)2*R_*H_*4, stream);   // h0 and c0
    hipLaunchKernelGGL(xo_kernel, dim3(R_, N2/256), dim3(256), 0, stream,
                       input_ids, d_in[2], d_in[3], d_in[8], XO, flags);

    float *hc = h0, *cc = c0, *hn = h1, *cn = c1;
    for (int st = 0; st < NST; ++st){
        hipMemsetAsync(scat, 0, (size_t)2*R_*H_*4, stream);  // scat + c_scat
        hipLaunchKernelGGL(t_kernel, dim3(R_, N2/256), dim3(256), 0, stream,
                           hc, d_in[4], d_in[6], d_in[9], d_in[11], d_in[13], d_in[15],
                           d_in[5], d_in[7], d_in[10], d_in[12], d_in[14], d_in[16],
                           T, flags);
        hipLaunchKernelGGL(scat_kernel, dim3(R_), dim3(256), 0, stream,
                           tree, st, T, XO, cc, scat, c_scat, flags);
        hipLaunchKernelGGL(full_kernel, dim3(R_), dim3(256), 0, stream,
                           XO, scat, c_scat, hfull, cfull);
        hipLaunchKernelGGL(ms_kernel, dim3(R_), dim3(256), 0, stream,
                           hfull, cfull, hc, cc, hn, cn, msk, rnk, st);
        float* th = hc; hc = hn; hn = th;
        float* tc = cc; cc = cn; cn = tc;
    }
    // Reference output dtype is float32 -> d_out is float*.
    hipMemcpyAsync(d_out, hc, (size_t)R_*H_*4, hipMemcpyDeviceToDevice, stream);
}

// Round 5
// 406.793 us; speedup vs baseline: 6.8535x; 6.8535x over previous
//
#include <hip/hip_runtime.h>
#include <hip/hip_bf16.h>

#define B_ 8
#define S_ 128
#define H_ 512
#define E_ 512
#define NST 8
#define R_ 1024         // flat rows
#define N2 2048         // packed GEMM width / T,XO row width
#define KD 512          // GEMM K depth
#define LDA 72          // LDS row pitch in shorts (pad 64 -> 72: 2-way max conflict)

typedef __hip_bfloat16 bf16;
typedef __attribute__((ext_vector_type(8))) short v8s;
typedef __attribute__((ext_vector_type(4))) float v4f;

__device__ __forceinline__ float sigm(float x){ return 1.0f/(1.0f + expf(-x)); }
__device__ __forceinline__ float load_in(const void* p, long long i, int isb){
    return isb ? __bfloat162float(((const bf16*)p)[i]) : ((const float*)p)[i];
}
__device__ __forceinline__ int idx_read(const int* p, int j, int is64){
    return is64 ? p[2*j] : p[j];
}
__device__ __forceinline__ unsigned short f2b(float v){
    bf16 b = __float2bfloat16(v);
    return *(unsigned short*)&b;
}

// ---- per-tensor float-storage probe (bf16=1 / fp32=0), as validated in r4 ----
__global__ void probe_f(const void* t0, const void* t1, const void* t2, const void* t3,
                        const void* t4, const void* t5, const void* t6, const void* t7,
                        const void* t8, const void* t9, const void* t10, const void* t11,
                        const void* t12, const void* t13, const void* t14,
                        int* __restrict__ flags){
    const void* ts[15] = {t0,t1,t2,t3,t4,t5,t6,t7,t8,t9,t10,t11,t12,t13,t14};
    const unsigned short* u = (const unsigned short*)ts[blockIdx.x];
    int t = threadIdx.x;      // 512
    int e = (u[t] >> 7) & 0xFF;
    unsigned long long b = __ballot(e >= 140);
    __shared__ int acc[8];
    if ((t & 63) == 0) acc[t >> 6] = (b != 0ull) ? 1 : 0;
    __syncthreads();
    if (t == 0){
        int any = 0;
        for (int w = 0; w < 8; ++w) any |= acc[w];
        flags[blockIdx.x] = any ? 0 : 1;
    }
}

__global__ void probe_i(const int* __restrict__ ids, const int* __restrict__ tree,
                        int* __restrict__ flags){
    const int* p = (blockIdx.x == 0) ? ids : tree;
    int n = (blockIdx.x == 0) ? 1024 : 2048;
    int t = threadIdx.x;   // 1024
    int nz = 0;
    for (int j = t; j < n; j += 1024)
        if (j & 1) nz |= (p[j] != 0);
    unsigned long long b = __ballot(nz);
    __shared__ int acc[16];
    if ((t & 63) == 0) acc[t >> 6] = (b != 0ull) ? 1 : 0;
    __syncthreads();
    if (t == 0){
        int any = 0;
        for (int w = 0; w < 16; ++w) any |= acc[w];
        flags[16 + blockIdx.x] = any ? 0 : 1;
    }
}

// ---- ballot-based mask + global-compaction rank (r2/r3 cross-validated) ----
__global__ void rank_kernel(const int* __restrict__ tree, int* __restrict__ msk,
                            int* __restrict__ rnk, const int* __restrict__ flags){
    int is64 = flags[17];
    int st = blockIdx.x;
    int t  = threadIdx.x;                 // 0..1023 == b*S+s
    int b = t >> 7, s = t & 127;
    int idx_d = idx_read(tree, ((b*NST + st)*3 + 0)*S_ + s, is64);
    int m = (idx_d != 0) ? 1 : 0;
    unsigned long long bal = __ballot(m);
    int lane = t & 63, wave = t >> 6;
    __shared__ int wtot[16];
    if (lane == 0) wtot[wave] = __popcll(bal);
    __syncthreads();
    int base = 0;
    for (int w = 0; w < wave; ++w) base += wtot[w];
    int rank = base + __popcll(bal & ((1ull << lane) - 1ull));
    msk[st*R_ + t] = m;
    rnk[st*R_ + t] = m ? rank : 0;
}

// ---- pack WxT[n][k] = (n<1536 ? W_ioux[k][n] : W_fx[k][n-1536]) as bf16 ----
// grid: (8, 64): x covers n (8*256), y = k-chunk of 8. Lanes consecutive in n -> coalesced reads.
__global__ __launch_bounds__(256)
void pack_wxt(const void* __restrict__ Wioux, const void* __restrict__ Wfx,
              unsigned short* __restrict__ WxT, const int* __restrict__ flags){
    int f_wx = flags[1], f_wf = flags[6];
    int n = blockIdx.x*256 + threadIdx.x;
    int k0 = blockIdx.y*8;
    unsigned short tmp[8];
    #pragma unroll
    for (int i = 0; i < 8; ++i){
        float v = (n < 1536) ? load_in(Wioux, (long long)(k0+i)*1536 + n, f_wx)
                             : load_in(Wfx,   (long long)(k0+i)*512 + (n-1536), f_wf);
        tmp[i] = f2b(v);
    }
    *(v8s*)&WxT[(size_t)n*KD + k0] = *(v8s*)tmp;
}

// ---- pack WcatT[n][k] = [Wr[:,:512] | Wl[:,:512] | Wfh0+Wfh1 | Wfh2+Wfh3]^T bf16 ----
__global__ __launch_bounds__(256)
void pack_wcatt(const void* __restrict__ Wr, const void* __restrict__ Wl,
                const void* __restrict__ W0, const void* __restrict__ W1,
                const void* __restrict__ W2, const void* __restrict__ W3,
                unsigned short* __restrict__ WcatT, const int* __restrict__ flags){
    int fWr=flags[2], fWl=flags[4], fW0=flags[7], fW1=flags[9], fW2=flags[11], fW3=flags[13];
    int n = blockIdx.x*256 + threadIdx.x;
    int k0 = blockIdx.y*8;
    unsigned short tmp[8];
    #pragma unroll
    for (int i = 0; i < 8; ++i){
        long long k = k0 + i;
        float v;
        if      (n <  512) v = load_in(Wr, k*1536 + n, fWr);
        else if (n < 1024) v = load_in(Wl, k*1536 + (n-512), fWl);
        else if (n < 1536) { int c = n-1024; v = load_in(W0, k*512+c, fW0) + load_in(W1, k*512+c, fW1); }
        else               { int c = n-1536; v = load_in(W2, k*512+c, fW2) + load_in(W3, k*512+c, fW3); }
        tmp[i] = f2b(v);
    }
    *(v8s*)&WcatT[(size_t)n*KD + k0] = *(v8s*)tmp;
}

__global__ void pack_bcat(const void* __restrict__ br, const void* __restrict__ bl,
                          const void* __restrict__ b0, const void* __restrict__ b1,
                          const void* __restrict__ b2, const void* __restrict__ b3,
                          float* __restrict__ bcat, const int* __restrict__ flags){
    int fbr=flags[3], fbl=flags[5], fb0=flags[8], fb1=flags[10], fb2=flags[12], fb3=flags[14];
    int n = blockIdx.x*256 + threadIdx.x;   // 2048
    float v;
    if      (n <  512) v = load_in(br, n, fbr);
    else if (n < 1024) v = load_in(bl, n-512, fbl);
    else if (n < 1536) v = load_in(b0, n-1024, fb0) + load_in(b1, n-1024, fb1);
    else               v = load_in(b2, n-1536, fb2) + load_in(b3, n-1536, fb3);
    bcat[n] = v;
}

// ---- xb[r][e] = bf16(emb[ids[r]][e]) : A-operand for the XO GEMM ----
__global__ __launch_bounds__(256)
void gather_xb(const int* __restrict__ ids, const void* __restrict__ emb,
               unsigned short* __restrict__ xb, const int* __restrict__ flags){
    int f_emb = flags[0], i64 = flags[16];
    int id = blockIdx.x*256 + threadIdx.x;   // 64K threads, 8 elems each
    int r = id >> 6, c0 = (id & 63)*8;
    long long base = (long long)idx_read(ids, r, i64)*E_ + c0;
    unsigned short tmp[8];
    #pragma unroll
    for (int i = 0; i < 8; ++i) tmp[i] = f2b(load_in(emb, base + i, f_emb));
    *(v8s*)&xb[(size_t)r*KD + c0] = *(v8s*)tmp;
}

// ---- MFMA GEMM: C[1024][2048] = A[1024][512]bf16 @ BT[2048][512]bf16^T (+bias) ----
// 128x128 tile, BK=64, 4 waves (2x2) of 64x64, mfma_f32_16x16x32_bf16.
__global__ __launch_bounds__(256)
void gemm_bf16(const unsigned short* __restrict__ A,
               const unsigned short* __restrict__ BT,
               const float* __restrict__ bias,
               float* __restrict__ C){
    __shared__ short As[128*LDA];
    __shared__ short Bs[128*LDA];
    int bn = blockIdx.x, bm = blockIdx.y;
    int tid = threadIdx.x;
    int lane = tid & 63, wave = tid >> 6;
    int wm = wave & 1, wn = wave >> 1;
    int lm = lane & 15, quad = lane >> 4;
    v4f acc[4][4];
    #pragma unroll
    for (int i=0;i<4;++i)
        #pragma unroll
        for (int j=0;j<4;++j) acc[i][j] = (v4f)0.0f;

    int srow = tid >> 3, scol = (tid & 7)*8;     // staging: 32 rows x 64k per pass
    for (int k0 = 0; k0 < KD; k0 += 64){
        __syncthreads();
        #pragma unroll
        for (int pass = 0; pass < 4; ++pass){
            int row = pass*32 + srow;
            v8s a = *(const v8s*)(A  + (size_t)(bm*128+row)*KD + k0 + scol);
            v8s b = *(const v8s*)(BT + (size_t)(bn*128+row)*KD + k0 + scol);
            *(v8s*)&As[row*LDA + scol] = a;
            *(v8s*)&Bs[row*LDA + scol] = b;
        }
        __syncthreads();
        #pragma unroll
        for (int kk = 0; kk < 64; kk += 32){
            v8s af[4], bf[4];
            #pragma unroll
            for (int t = 0; t < 4; ++t){
                af[t] = *(const v8s*)&As[(wm*64 + t*16 + lm)*LDA + kk + quad*8];
                bf[t] = *(const v8s*)&Bs[(wn*64 + t*16 + lm)*LDA + kk + quad*8];
            }
            #pragma unroll
            for (int i = 0; i < 4; ++i)
                #pragma unroll
                for (int j = 0; j < 4; ++j)
                    acc[i][j] = __builtin_amdgcn_mfma_f32_16x16x32_bf16(af[i], bf[j], acc[i][j], 0, 0, 0);
        }
    }
    #pragma unroll
    for (int j = 0; j < 4; ++j){
        int n = bn*128 + wn*64 + j*16 + lm;
        float bv = bias ? bias[n] : 0.0f;
        #pragma unroll
        for (int i = 0; i < 4; ++i){
            int m0 = bm*128 + wm*64 + i*16 + quad*4;
            #pragma unroll
            for (int rg = 0; rg < 4; ++rg)
                C[(size_t)(m0+rg)*N2 + n] = acc[i][j][rg] + bv;
        }
    }
}

// ---- f-gate + the three scatter-adds (atomics) ----
__global__ __launch_bounds__(256)
void scat_kernel(const int* __restrict__ tree, int st,
                 const float* __restrict__ T, const float* __restrict__ XO,
                 const float* __restrict__ c_cur,
                 float* __restrict__ scat, float* __restrict__ c_scat,
                 const int* __restrict__ flags){
    int is64 = flags[17];
    int r = blockIdx.x;
    int b = r >> 7, s = r & 127;
    int base = (b*NST + st)*3*S_;
    int rd = (b<<7) + idx_read(tree, base + s, is64);
    int rr = (b<<7) + idx_read(tree, base + S_ + s, is64);
    int rl = (b<<7) + idx_read(tree, base + 2*S_ + s, is64);
    for (int c = threadIdx.x; c < H_; c += 256){
        float f = sigm(XO[(size_t)rd*N2 + 1536 + c]
                     + T [(size_t)rr*N2 + 1024 + c]
                     + T [(size_t)rl*N2 + 1536 + c]);
        atomicAdd(&c_scat[(size_t)rd*H_ + c], f * c_cur[(size_t)r*H_ + c]);
        atomicAdd(&scat  [(size_t)rr*H_ + c], T[(size_t)r*N2 + c]);
        atomicAdd(&scat  [(size_t)rl*H_ + c], T[(size_t)r*N2 + 512 + c]);
    }
}

// ---- fused gates + masked-scatter-gather + bf16 h for next GEMM ----
__global__ __launch_bounds__(256)
void step_epi(const float* __restrict__ XO, const float* __restrict__ scat,
              const float* __restrict__ c_scat,
              const float* __restrict__ h_old, const float* __restrict__ c_old,
              float* __restrict__ h_new, float* __restrict__ c_new,
              unsigned short* __restrict__ hb,
              const int* __restrict__ msk, const int* __restrict__ rnk, int st){
    int r = blockIdx.x;
    int m = msk[st*R_ + r];
    int j = rnk[st*R_ + r];     // source row of the compacted full-output
    if (m){
        const float* xo = XO + (size_t)j*N2;
        for (int c = threadIdx.x; c < H_; c += 256){
            float ig = sigm(xo[c] + scat[(size_t)j*H_ + c]);
            float og = sigm(xo[512 + c]);
            float ug = tanhf(xo[1024 + c]);
            float cf = ig*ug + c_scat[(size_t)j*H_ + c];
            float hf = og * tanhf(cf);
            h_new[(size_t)r*H_ + c] = hf;
            c_new[(size_t)r*H_ + c] = cf;
            hb[(size_t)r*KD + c] = f2b(hf);
        }
    } else {
        for (int c = threadIdx.x; c < H_; c += 256){
            float hv = h_old[(size_t)r*H_ + c];
            h_new[(size_t)r*H_ + c] = hv;
            c_new[(size_t)r*H_ + c] = c_old[(size_t)r*H_ + c];
            hb[(size_t)r*KD + c] = f2b(hv);
        }
    }
}

extern "C" void kernel_launch(void* const* d_in, const int* in_sizes, int n_in,
                              void* d_out, int out_size, void* d_ws, size_t ws_size,
                              hipStream_t stream) {
    const int* input_ids = (const int*)d_in[0];
    const int* tree      = (const int*)d_in[1];

    char* p = (char*)d_ws;
    auto alloc = [&](size_t bytes) -> void* {
        void* q = (void*)p;
        p += (bytes + 255) & ~(size_t)255;
        return q;
    };
    float*          XO     = (float*)alloc((size_t)R_*N2*4);       // 8 MB
    float*          T      = (float*)alloc((size_t)R_*N2*4);       // 8 MB
    float*          scat   = (float*)alloc((size_t)R_*H_*4);       // 2 MB (contig with c_scat)
    float*          c_scat = (float*)alloc((size_t)R_*H_*4);       // 2 MB
    float*          h0     = (float*)alloc((size_t)R_*H_*4);       // contig with c0
    float*          c0     = (float*)alloc((size_t)R_*H_*4);
    float*          h1     = (float*)alloc((size_t)R_*H_*4);
    float*          c1     = (float*)alloc((size_t)R_*H_*4);
    unsigned short* WxT    = (unsigned short*)alloc((size_t)N2*KD*2);  // 2 MB
    unsigned short* WcatT  = (unsigned short*)alloc((size_t)N2*KD*2);  // 2 MB
    float*          bcat   = (float*)alloc((size_t)N2*4);
    unsigned short* xb     = (unsigned short*)alloc((size_t)R_*KD*2);  // 1 MB
    unsigned short* hb     = (unsigned short*)alloc((size_t)R_*KD*2);  // 1 MB
    int*            msk    = (int*)alloc((size_t)NST*R_*4);
    int*            rnk    = (int*)alloc((size_t)NST*R_*4);
    int*            flags  = (int*)alloc(256);

    hipLaunchKernelGGL(probe_f, dim3(15), dim3(512), 0, stream,
                       d_in[2], d_in[3], d_in[4], d_in[5], d_in[6], d_in[7], d_in[8],
                       d_in[9], d_in[10], d_in[11], d_in[12], d_in[13], d_in[14],
                       d_in[15], d_in[16], flags);
    hipLaunchKernelGGL(probe_i, dim3(2), dim3(1024), 0, stream, input_ids, tree, flags);
    hipLaunchKernelGGL(rank_kernel, dim3(NST), dim3(R_), 0, stream, tree, msk, rnk, flags);
    hipLaunchKernelGGL(pack_wxt, dim3(8, 64), dim3(256), 0, stream,
                       d_in[3], d_in[8], WxT, flags);
    hipLaunchKernelGGL(pack_wcatt, dim3(8, 64), dim3(256), 0, stream,
                       d_in[4], d_in[6], d_in[9], d_in[11], d_in[13], d_in[15], WcatT, flags);
    hipLaunchKernelGGL(pack_bcat, dim3(8), dim3(256), 0, stream,
                       d_in[5], d_in[7], d_in[10], d_in[12], d_in[14], d_in[16], bcat, flags);
    hipLaunchKernelGGL(gather_xb, dim3(R_*KD/8/256), dim3(256), 0, stream,
                       input_ids, d_in[2], xb, flags);
    hipMemsetAsync(h0, 0, (size_t)2*R_*H_*4, stream);   // h0 and c0
    hipMemsetAsync(hb, 0, (size_t)R_*KD*2, stream);     // bf16 h for step 0

    // XO = xb @ WxT^T  (1024 x 2048, K=512), no bias
    hipLaunchKernelGGL(gemm_bf16, dim3(N2/128, R_/128), dim3(256), 0, stream,
                       xb, WxT, (const float*)nullptr, XO);

    float *hc = h0, *cc = c0, *hn = h1, *cn = c1;
    for (int st = 0; st < NST; ++st){
        hipMemsetAsync(scat, 0, (size_t)2*R_*H_*4, stream);  // scat + c_scat
        hipLaunchKernelGGL(gemm_bf16, dim3(N2/128, R_/128), dim3(256), 0, stream,
                           hb, WcatT, bcat, T);
        hipLaunchKernelGGL(scat_kernel, dim3(R_), dim3(256), 0, stream,
                           tree, st, T, XO, cc, scat, c_scat, flags);
        hipLaunchKernelGGL(step_epi, dim3(R_), dim3(256), 0, stream,
                           XO, scat, c_scat, hc, cc, hn, cn, hb, msk, rnk, st);
        float* th = hc; hc = hn; hn = th;
        float* tc = cc; cc = cn; cn = tc;
    }
    // output is fp32 (verified r4)
    hipMemcpyAsync(d_out, hc, (size_t)R_*H_*4, hipMemcpyDeviceToDevice, stream);
}